// Round 6
// baseline (274.997 us; speedup 1.0000x reference)
//
#include <hip/hip_runtime.h>

// GINE 2-layer GNN: N=50000 nodes, E=800000 edges, d=128.
// Round 18: one-pass ticket CSR build. Per-iteration accounting showed
// prep+scatter+csr ~ 90us (vs gine 2x43.8, fill 43.6): the 2-pass bucket
// sort (scatter 6.4MB random + csr read/sort/rewrite) was the biggest
// controllable chunk. gine_layer only needs off[] + node-grouped stage,
// so: per-NODE histogram (global atomics) -> 2 parallel scan kernels
// (49x1024, replaces round-17's serial 1-block scan_bases mistake) ->
// ticket_scatter writes each edge directly to its final slot via
// atomicAdd(&cur[dst],1). bucket_csr + G/P/B machinery deleted.
// gine_layer untouched (measured at ~85% of per-CU mem-path ceiling).
// bf16 feature path, f32 accumulation.

typedef unsigned long long u64;
typedef unsigned int u32;
typedef unsigned short ushort;
typedef __attribute__((ext_vector_type(8))) short short8;
typedef __attribute__((ext_vector_type(4))) float f32x4;
typedef __attribute__((ext_vector_type(2))) float f32x2;
typedef __attribute__((ext_vector_type(4))) u32 u32x4;   // native vec for NT ops

constexpr int NN = 50000;
constexpr int NE = 800000;
constexpr int D  = 128;
constexpr int NC  = 128;                  // edge chunks (hist phase)
constexpr int CHUNK = NE / NC;            // 6250
constexpr int GR = 32;                    // GEMM rows per block
constexpr int GG = (NN + GR - 1) / GR;    // 1563
constexpr int CBLK = NN * D / 8 / 256;    // 3125 cast blocks (exact)
constexpr int SCB = (NN + 1023) / 1024;   // 49 scan blocks

__device__ __forceinline__ ushort f2bf(float f) {
    u32 u = __float_as_uint(f);
    return (ushort)((u + 0x7FFFu + ((u >> 16) & 1u)) >> 16);
}
__device__ __forceinline__ float bfl(u32 u) {            // low bf16 -> f32
    return __uint_as_float(u << 16);
}
__device__ __forceinline__ float bfh(u32 u) {            // high bf16 -> f32
    return __uint_as_float(u & 0xFFFF0000u);
}
__device__ __forceinline__ f32x2 unpk(u32 u) {           // packed bf16 -> 2xf32
    f32x2 r; r.x = bfl(u); r.y = bfh(u); return r;
}

// ---- prep+hist: cast x -> bf16, transpose+cast W1/W2, per-NODE histogram --

__global__ __launch_bounds__(256) void prep_hist(
    const float* __restrict__ x,  ushort* __restrict__ xb,
    const float* __restrict__ W1, const float* __restrict__ W2,
    ushort* __restrict__ Wt1, ushort* __restrict__ Wt2,
    const int* __restrict__ dst, int* __restrict__ cnt)
{
    int blk = blockIdx.x;
    if (blk < CBLK) {
        int base = (blk * 256 + threadIdx.x) * 8;
        float4 a = *(const float4*)(x + base);
        float4 b = *(const float4*)(x + base + 4);
        uint4 o;
        o.x = (u32)f2bf(a.x) | ((u32)f2bf(a.y) << 16);
        o.y = (u32)f2bf(a.z) | ((u32)f2bf(a.w) << 16);
        o.z = (u32)f2bf(b.x) | ((u32)f2bf(b.y) << 16);
        o.w = (u32)f2bf(b.z) | ((u32)f2bf(b.w) << 16);
        *(uint4*)(xb + base) = o;
    } else if (blk < CBLK + 8) {
        int b = blk - CBLK;                 // 0..7
        const float* W  = (b >= 4) ? W2 : W1;
        ushort*      Wt = (b >= 4) ? Wt2 : Wt1;
        int k0 = (b & 3) * 32;
        for (int i = threadIdx.x; i < 32 * D; i += 256) {
            int n = i >> 5, r = i & 31;
            Wt[n * D + k0 + r] = f2bf(W[(k0 + r) * D + n]);
        }
    } else {
        int t = threadIdx.x, c = blk - CBLK - 8;
        int e0 = c * CHUNK;
        for (int i = t; i < CHUNK; i += 256)
            atomicAdd(&cnt[dst[e0 + i]], 1);
    }
}

// ---- scan1: block-local exclusive scan of cnt + block totals ----

__global__ __launch_bounds__(1024) void scan1(
    const int* __restrict__ cnt, int* __restrict__ off, int* __restrict__ S)
{
    __shared__ int ts[1024];
    int b = blockIdx.x, t = threadIdx.x, i = b * 1024 + t;
    int v = (i < NN) ? cnt[i] : 0;
    ts[t] = v;
    __syncthreads();
    for (int d = 1; d < 1024; d <<= 1) {
        int u = (t >= d) ? ts[t - d] : 0;
        __syncthreads();
        ts[t] += u;
        __syncthreads();
    }
    if (i < NN) off[i] = ts[t] - v;        // block-local exclusive
    if (t == 1023) S[b] = ts[1023];        // block total
}

// ---- scan2: add block-prefix, publish off[] and cur[] (= ticket cursors) --

__global__ __launch_bounds__(1024) void scan2(
    const int* __restrict__ S, int* __restrict__ off, int* __restrict__ cur)
{
    __shared__ int base_s;
    int b = blockIdx.x, t = threadIdx.x, i = b * 1024 + t;
    if (t < 64) {                           // SCB=49 < 64
        int v = (t < b) ? S[t] : 0;
        #pragma unroll
        for (int o = 32; o; o >>= 1) v += __shfl_down(v, o, 64);
        if (t == 0) base_s = v;
    }
    __syncthreads();
    int base = base_s;
    if (i < NN) {
        int o = off[i] + base;
        off[i] = o;
        cur[i] = o;
    }
    if (b == 0 && t == 0) off[NN] = NE;
}

// ---- ticket_scatter: one pass, write edge to its final CSR slot ----

__global__ __launch_bounds__(256) void ticket_scatter(
    const int*   __restrict__ src,
    const int*   __restrict__ dst,
    const float* __restrict__ ew,
    int*         __restrict__ cur,
    u64*         __restrict__ stage)
{
    int e = blockIdx.x * 256 + threadIdx.x;
    if (e >= NE) return;
    int d = dst[e];
    int slot = atomicAdd(&cur[d], 1);
    stage[slot] = ((u64)__float_as_uint(ew[e]) << 32) | (u32)src[e];
}

// ---- fused layer: aggregate (gather, packed f32 acc) + self + MFMA gemm --
// out = (relu?)((h + sum_{e->n} relu(h[src_e] + w_e*We + be)) @ W + bias)

__global__ __launch_bounds__(256, 4) void gine_layer(
    const ushort* __restrict__ hb,     // input features bf16 [NN][D]
    const int*    __restrict__ off,    // CSR offsets into sorted stage
    const u64*    __restrict__ epk,    // packed edges, grouped by dst
    const float*  __restrict__ We,
    const float*  __restrict__ be,
    const ushort* __restrict__ Wtb,    // transposed weight bf16 [D][D]
    const float*  __restrict__ bias,
    float*        __restrict__ outf,   // layer 2 (or null)
    ushort*       __restrict__ outb,   // layer 1 (or null)
    int relu)
{
    __shared__ ushort As[GR * 140];    // 9 KB -- only LDS in the kernel

    const int t    = threadIdx.x;
    const int row0 = blockIdx.x * GR;

    // ---- phase 1: aggregate edges + self term -> As (bf16) ----
    // 16 lanes per node, 8 features per lane (4x f32x2), 8-deep edge
    // unroll, one-iteration-ahead prefetch of the packed-edge words.
    const int g  = t >> 4;             // node group 0..15
    const int d8 = (t & 15) << 3;

    f32x2 wv[4], bv[4];
    #pragma unroll
    for (int j = 0; j < 4; ++j) {
        wv[j] = *(const f32x2*)(We + d8 + 2 * j);
        bv[j] = *(const f32x2*)(be + d8 + 2 * j);
    }
    const f32x2 zero2 = {0.f, 0.f};

    for (int nrep = 0; nrep < GR / 16; ++nrep) {
        int ln = nrep * 16 + g;        // local row 0..GR-1
        int n  = row0 + ln;
        f32x2 a[4] = {zero2, zero2, zero2, zero2};
        if (n < NN) {
            // self term: issue early, consume after the edge loop
            u32x4 sv = *(const u32x4*)(hb + (size_t)n * D + d8);
            int e0 = off[n], e1 = off[n + 1];
            u64 p[8];
            int m0 = e1 - e0; if (m0 > 8) m0 = 8;
            #pragma unroll
            for (int k = 0; k < 8; ++k) p[k] = (k < m0) ? epk[e0 + k] : 0;
            for (int e = e0; e < e1; e += 8) {
                int m = e1 - e; if (m > 8) m = 8;
                u32x4 hv[8];
                #pragma unroll
                for (int k = 0; k < 8; ++k)
                    hv[k] = *(const u32x4*)(hb + (size_t)(p[k] & 0x1FFFF) * D + d8);
                // prefetch next iteration's packed edges under the hv wait
                u64 pn[8];
                int mn = e1 - (e + 8); if (mn > 8) mn = 8;
                #pragma unroll
                for (int k = 0; k < 8; ++k)
                    pn[k] = (k < mn) ? epk[e + 8 + k] : 0;
                #pragma unroll
                for (int k = 0; k < 8; ++k) {
                    if (k < m) {
                        float w = __uint_as_float((u32)(p[k] >> 32));
                        f32x2 w2 = {w, w};
                        a[0] += __builtin_elementwise_max(zero2,
                                  unpk(hv[k].x) + __builtin_elementwise_fma(w2, wv[0], bv[0]));
                        a[1] += __builtin_elementwise_max(zero2,
                                  unpk(hv[k].y) + __builtin_elementwise_fma(w2, wv[1], bv[1]));
                        a[2] += __builtin_elementwise_max(zero2,
                                  unpk(hv[k].z) + __builtin_elementwise_fma(w2, wv[2], bv[2]));
                        a[3] += __builtin_elementwise_max(zero2,
                                  unpk(hv[k].w) + __builtin_elementwise_fma(w2, wv[3], bv[3]));
                    }
                }
                #pragma unroll
                for (int k = 0; k < 8; ++k) p[k] = pn[k];
            }
            // self term (h_n), f32 add before the single bf16 rounding
            a[0] += unpk(sv.x);
            a[1] += unpk(sv.y);
            a[2] += unpk(sv.z);
            a[3] += unpk(sv.w);
        }
        uint2 lo, hi;
        lo.x = (u32)f2bf(a[0].x) | ((u32)f2bf(a[0].y) << 16);
        lo.y = (u32)f2bf(a[1].x) | ((u32)f2bf(a[1].y) << 16);
        hi.x = (u32)f2bf(a[2].x) | ((u32)f2bf(a[2].y) << 16);
        hi.y = (u32)f2bf(a[3].x) | ((u32)f2bf(a[3].y) << 16);
        *(uint2*)&As[ln * 140 + d8]     = lo;
        *(uint2*)&As[ln * 140 + d8 + 4] = hi;
    }
    __syncthreads();

    // ---- phase 2: MFMA gemm, 32x128 output; B-fragments straight from
    // global (L2-resident 32 KB, shared by all blocks; MFMA ~1% of time) ----
    const int wave = t >> 6;           // 0..3 -> 32-col slab
    const int lane = t & 63;
    const int q    = lane >> 4;
    const int m    = lane & 15;
    const int wc   = wave * 32;

    f32x4 acc[2][2] = {};
    #pragma unroll
    for (int kb = 0; kb < 4; ++kb) {
        int ak = kb * 32 + q * 8;
        short8 af[2];
        #pragma unroll
        for (int rg = 0; rg < 2; ++rg)
            af[rg] = *(const short8*)&As[(rg * 16 + m) * 140 + ak];
        #pragma unroll
        for (int ct = 0; ct < 2; ++ct) {
            short8 bf = *(const short8*)(Wtb + (wc + ct * 16 + m) * D + ak);
            #pragma unroll
            for (int rg = 0; rg < 2; ++rg)
                acc[rg][ct] = __builtin_amdgcn_mfma_f32_16x16x32_bf16(
                    af[rg], bf, acc[rg][ct], 0, 0, 0);
        }
    }

    #pragma unroll
    for (int ct = 0; ct < 2; ++ct) {
        int col = wc + ct * 16 + m;
        float bc = bias[col];
        #pragma unroll
        for (int rg = 0; rg < 2; ++rg) {
            #pragma unroll
            for (int r = 0; r < 4; ++r) {
                int grow = row0 + rg * 16 + q * 4 + r;
                if (grow < NN) {
                    float v = acc[rg][ct][r] + bc;
                    if (relu) v = fmaxf(0.f, v);
                    if (outb) outb[(size_t)grow * D + col] = f2bf(v);
                    else __builtin_nontemporal_store(v, outf + (size_t)grow * D + col);
                }
            }
        }
    }
}

extern "C" void kernel_launch(void* const* d_in, const int* in_sizes, int n_in,
                              void* d_out, int out_size, void* d_ws, size_t ws_size,
                              hipStream_t stream)
{
    const float* x   = (const float*)d_in[0];
    const int*   ei  = (const int*)  d_in[1];
    const float* ew  = (const float*)d_in[2];
    const float* We1 = (const float*)d_in[3];
    const float* be1 = (const float*)d_in[4];
    const float* W1  = (const float*)d_in[5];
    const float* b1  = (const float*)d_in[6];
    const float* We2 = (const float*)d_in[7];
    const float* be2 = (const float*)d_in[8];
    const float* W2  = (const float*)d_in[9];
    const float* b2  = (const float*)d_in[10];

    float* out = (float*)d_out;

    // workspace (~33 MB)
    ushort* xb   = (ushort*)d_ws;                    // NN*D bf16
    ushort* hb   = xb + (size_t)NN * D;              // NN*D
    ushort* Wt1  = hb + (size_t)NN * D;              // 16384
    ushort* Wt2  = Wt1 + D * D;                      // 16384
    u64*   stage = (u64*)(Wt2 + D * D);              // NE u64
    int*   cnt   = (int*)(stage + NE);               // NN
    int*   off   = cnt + NN;                         // NN+1
    int*   cur   = off + NN + 1;                     // NN
    int*   S     = cur + NN;                         // SCB

    const int* src = ei;
    const int* dst = ei + NE;

    // cnt must be zero before prep_hist's atomics (workspace is poisoned)
    hipMemsetAsync(cnt, 0, NN * sizeof(int), stream);

    // ---- prep (cast x, transpose W) + per-node histogram, one launch ----
    prep_hist<<<CBLK + 8 + NC, 256, 0, stream>>>(x, xb, W1, W2, Wt1, Wt2,
                                                 dst, cnt);

    // ---- CSR offsets (two parallel scan kernels) ----
    scan1<<<SCB, 1024, 0, stream>>>(cnt, off, S);
    scan2<<<SCB, 1024, 0, stream>>>(S, off, cur);

    // ---- one-pass ticket scatter into final CSR order ----
    ticket_scatter<<<(NE + 255) / 256, 256, 0, stream>>>(src, dst, ew, cur,
                                                         stage);

    // ---- layer 1 (fused aggregate + gemm) ----
    gine_layer<<<GG, 256, 0, stream>>>(xb, off, stage, We1, be1, Wt1, b1,
                                       nullptr, hb, 1);

    // ---- layer 2 (fused aggregate + gemm) ----
    gine_layer<<<GG, 256, 0, stream>>>(hb, off, stage, We2, be2, Wt2, b2,
                                       out, nullptr, 0);
}

// Round 7
// 209.381 us; speedup vs baseline: 1.3134x; 1.3134x over previous
//
#include <hip/hip_runtime.h>

// GINE 2-layer GNN: N=50000 nodes, E=800000 edges, d=128.
// Round 19: revert to the round-16 bucket pipeline (220.9us verified; the
// round-18 global-atomic build was a dead end: device-scope atomics resolve
// at the far coherence point, ~13 Gops/s, prep_hist 63-70us). One change:
// move the x->bf16 cast (38MB streaming) out of prep_hist into bucket_csr's
// grid -- csr is a latency/LDS-bound sort with idle memory pipes, so the
// cast traffic hides under it, and prep shrinks to a 136-block hist+W
// kernel. Chain: hist_w -> scatter -> csr_cast -> gine x2.
// gine_layer: GR=32, (256,4), pk-f32 math (round-17, neutral), kept as-is.
// bf16 feature path, f32 accumulation.

typedef unsigned long long u64;
typedef unsigned int u32;
typedef unsigned short ushort;
typedef __attribute__((ext_vector_type(8))) short short8;
typedef __attribute__((ext_vector_type(4))) float f32x4;
typedef __attribute__((ext_vector_type(2))) float f32x2;
typedef __attribute__((ext_vector_type(4))) u32 u32x4;   // native vec for NT ops

constexpr int NN = 50000;
constexpr int NE = 800000;
constexpr int D  = 128;
constexpr int BSH = 6;                    // 64 nodes per bucket
constexpr int NB  = (NN + 63) >> BSH;     // 782 buckets
constexpr int NC  = 128;                  // edge chunks
constexpr int CHUNK = NE / NC;            // 6250
constexpr int BCAP = 4096;
constexpr int GR = 32;                    // GEMM rows per block
constexpr int GG = (NN + GR - 1) / GR;    // 1563
constexpr int NU4 = NN * D / 8;           // 800000 uint4s to cast
constexpr int CPB = 1024;                 // cast uint4s per csr block

__device__ __forceinline__ ushort f2bf(float f) {
    u32 u = __float_as_uint(f);
    return (ushort)((u + 0x7FFFu + ((u >> 16) & 1u)) >> 16);
}
__device__ __forceinline__ float bfl(u32 u) {            // low bf16 -> f32
    return __uint_as_float(u << 16);
}
__device__ __forceinline__ float bfh(u32 u) {            // high bf16 -> f32
    return __uint_as_float(u & 0xFFFF0000u);
}
__device__ __forceinline__ f32x2 unpk(u32 u) {           // packed bf16 -> 2xf32
    f32x2 r; r.x = bfl(u); r.y = bfh(u); return r;
}
__device__ __forceinline__ u64 pack_edge(int src, int d6, float w) {
    return ((u64)__float_as_uint(w) << 32) | (u32)(src | (d6 << 17));
}

// ---- hist_w: dst histogram (LDS) + transpose+cast W1/W2 ----

__global__ __launch_bounds__(256) void hist_w(
    const float* __restrict__ W1, const float* __restrict__ W2,
    ushort* __restrict__ Wt1, ushort* __restrict__ Wt2,
    const int* __restrict__ dst, int* __restrict__ G)
{
    int blk = blockIdx.x;
    if (blk < NC) {
        __shared__ int hh[NB];
        int t = threadIdx.x, c = blk;
        for (int i = t; i < NB; i += 256) hh[i] = 0;
        __syncthreads();
        int e0 = c * CHUNK;
        for (int i = t; i < CHUNK; i += 256)
            atomicAdd(&hh[dst[e0 + i] >> BSH], 1);
        __syncthreads();
        for (int i = t; i < NB; i += 256) G[c * NB + i] = hh[i];
    } else {
        int b = blk - NC;                   // 0..7
        const float* W  = (b >= 4) ? W2 : W1;
        ushort*      Wt = (b >= 4) ? Wt2 : Wt1;
        int k0 = (b & 3) * 32;
        for (int i = threadIdx.x; i < 32 * D; i += 256) {
            int n = i >> 5, r = i & 31;
            Wt[n * D + k0 + r] = f2bf(W[(k0 + r) * D + n]);
        }
    }
}

// ---- bucket_scatter, 1024 threads/block, in-kernel column scan ----

__global__ __launch_bounds__(1024) void bucket_scatter(
    const int*   __restrict__ src,
    const int*   __restrict__ dst,
    const float* __restrict__ ew,
    const int*   __restrict__ G,
    int*         __restrict__ B,
    u64*         __restrict__ stage)
{
    __shared__ int base_s[NB];
    __shared__ int cnt_s[NB];
    __shared__ int pre_s[NB];
    __shared__ int tsum[1024];
    const int t = threadIdx.x, c = blockIdx.x;

    // phase A: bucket total S and my column prefix P (chunks < c); one b/thread
    int S = 0, P = 0;
    if (t < NB) {
        #pragma unroll 8
        for (int cc = 0; cc < NC; ++cc) {
            int g = G[cc * NB + t];
            S += g;
            if (cc < c) P += g;
        }
        pre_s[t] = P;
    }
    tsum[t] = S;
    __syncthreads();

    // phase B: exclusive scan of the 1024 (>=NB) bucket totals
    for (int d = 1; d < 1024; d <<= 1) {
        int v = (t >= d) ? tsum[t - d] : 0;
        __syncthreads();
        tsum[t] += v;
        __syncthreads();
    }
    if (t < NB) base_s[t] = tsum[t] - S;       // exclusive bucket start
    __syncthreads();

    if (c == 0) {                               // publish B for bucket_csr
        if (t < NB) B[t] = base_s[t];
        if (t == 0) B[NB] = NE;
    }
    if (t < NB) {
        base_s[t] += pre_s[t];
        cnt_s[t] = 0;
    }
    __syncthreads();

    // phase C: scatter my chunk (16 waves -> latency hidden)
    int e0 = c * CHUNK;
    for (int i = t; i < CHUNK; i += 1024) {
        int e  = e0 + i;
        int d  = dst[e];
        int bk = d >> BSH;
        int r  = atomicAdd(&cnt_s[bk], 1);
        stage[base_s[bk] + r] = pack_edge(src[e], d & 63, ew[e]);
    }
}

// per bucket: counting sort by node, contiguous writeback, per-node offsets.
// ALSO casts a chunk of x -> bf16 (streaming work hidden under sort latency).
__global__ __launch_bounds__(256) void bucket_csr_cast(
    const int* __restrict__ B, u64* __restrict__ stage, int* __restrict__ off,
    const float* __restrict__ x, ushort* __restrict__ xb)
{
    __shared__ u64 buf[BCAP];           // 32 KB
    __shared__ int cnt[64];
    __shared__ int cur[64];
    __shared__ int noff[64];
    int t = threadIdx.x, b = blockIdx.x;

    // ---- cast fragment: 4 uint4 (32 bf16) per thread ----
    #pragma unroll
    for (int j = 0; j < CPB / 256; ++j) {
        int i = b * CPB + j * 256 + t;
        if (i < NU4) {
            int base = i * 8;
            float4 a = *(const float4*)(x + base);
            float4 c = *(const float4*)(x + base + 4);
            uint4 o;
            o.x = (u32)f2bf(a.x) | ((u32)f2bf(a.y) << 16);
            o.y = (u32)f2bf(a.z) | ((u32)f2bf(a.w) << 16);
            o.z = (u32)f2bf(c.x) | ((u32)f2bf(c.y) << 16);
            o.w = (u32)f2bf(c.z) | ((u32)f2bf(c.w) << 16);
            *(uint4*)(xb + base) = o;
        }
    }

    // ---- counting sort of this bucket ----
    int e0 = B[b], e1 = B[b + 1];
    int n = e1 - e0;
    if (n > BCAP) n = BCAP;
    if (t < 64) { cnt[t] = 0; cur[t] = 0; }
    __syncthreads();
    for (int i = t; i < n; i += 256)
        atomicAdd(&cnt[(int)((stage[e0 + i] >> 17) & 63)], 1);
    __syncthreads();
    if (t == 0) {
        int run = 0;
        for (int j = 0; j < 64; ++j) { noff[j] = run; run += cnt[j]; }
    }
    __syncthreads();
    int n0 = b << BSH;
    if (t < 64 && (n0 + t) < NN) off[n0 + t] = e0 + noff[t];
    if (b == NB - 1 && t == 0) off[NN] = NE;
    for (int i = t; i < n; i += 256) {
        u64 p = stage[e0 + i];
        int d6 = (int)((p >> 17) & 63);
        int r = atomicAdd(&cur[d6], 1);
        buf[noff[d6] + r] = p;
    }
    __syncthreads();
    for (int i = t; i < n; i += 256) stage[e0 + i] = buf[i];
}

// ---- fused layer: aggregate (gather, packed f32 acc) + self + MFMA gemm --
// out = (relu?)((h + sum_{e->n} relu(h[src_e] + w_e*We + be)) @ W + bias)

__global__ __launch_bounds__(256, 4) void gine_layer(
    const ushort* __restrict__ hb,     // input features bf16 [NN][D]
    const int*    __restrict__ off,    // CSR offsets into sorted stage
    const u64*    __restrict__ epk,    // sorted packed edges
    const float*  __restrict__ We,
    const float*  __restrict__ be,
    const ushort* __restrict__ Wtb,    // transposed weight bf16 [D][D]
    const float*  __restrict__ bias,
    float*        __restrict__ outf,   // layer 2 (or null)
    ushort*       __restrict__ outb,   // layer 1 (or null)
    int relu)
{
    __shared__ ushort As[GR * 140];    // 9 KB -- only LDS in the kernel

    const int t    = threadIdx.x;
    const int row0 = blockIdx.x * GR;

    // ---- phase 1: aggregate edges + self term -> As (bf16) ----
    // 16 lanes per node, 8 features per lane (4x f32x2), 8-deep edge
    // unroll, one-iteration-ahead prefetch of the packed-edge words.
    const int g  = t >> 4;             // node group 0..15
    const int d8 = (t & 15) << 3;

    f32x2 wv[4], bv[4];
    #pragma unroll
    for (int j = 0; j < 4; ++j) {
        wv[j] = *(const f32x2*)(We + d8 + 2 * j);
        bv[j] = *(const f32x2*)(be + d8 + 2 * j);
    }
    const f32x2 zero2 = {0.f, 0.f};

    for (int nrep = 0; nrep < GR / 16; ++nrep) {
        int ln = nrep * 16 + g;        // local row 0..GR-1
        int n  = row0 + ln;
        f32x2 a[4] = {zero2, zero2, zero2, zero2};
        if (n < NN) {
            // self term: issue early, consume after the edge loop
            u32x4 sv = *(const u32x4*)(hb + (size_t)n * D + d8);
            int e0 = off[n], e1 = off[n + 1];
            u64 p[8];
            int m0 = e1 - e0; if (m0 > 8) m0 = 8;
            #pragma unroll
            for (int k = 0; k < 8; ++k) p[k] = (k < m0) ? epk[e0 + k] : 0;
            for (int e = e0; e < e1; e += 8) {
                int m = e1 - e; if (m > 8) m = 8;
                u32x4 hv[8];
                #pragma unroll
                for (int k = 0; k < 8; ++k)
                    hv[k] = *(const u32x4*)(hb + (size_t)(p[k] & 0x1FFFF) * D + d8);
                // prefetch next iteration's packed edges under the hv wait
                u64 pn[8];
                int mn = e1 - (e + 8); if (mn > 8) mn = 8;
                #pragma unroll
                for (int k = 0; k < 8; ++k)
                    pn[k] = (k < mn) ? epk[e + 8 + k] : 0;
                #pragma unroll
                for (int k = 0; k < 8; ++k) {
                    if (k < m) {
                        float w = __uint_as_float((u32)(p[k] >> 32));
                        f32x2 w2 = {w, w};
                        a[0] += __builtin_elementwise_max(zero2,
                                  unpk(hv[k].x) + __builtin_elementwise_fma(w2, wv[0], bv[0]));
                        a[1] += __builtin_elementwise_max(zero2,
                                  unpk(hv[k].y) + __builtin_elementwise_fma(w2, wv[1], bv[1]));
                        a[2] += __builtin_elementwise_max(zero2,
                                  unpk(hv[k].z) + __builtin_elementwise_fma(w2, wv[2], bv[2]));
                        a[3] += __builtin_elementwise_max(zero2,
                                  unpk(hv[k].w) + __builtin_elementwise_fma(w2, wv[3], bv[3]));
                    }
                }
                #pragma unroll
                for (int k = 0; k < 8; ++k) p[k] = pn[k];
            }
            // self term (h_n), f32 add before the single bf16 rounding
            a[0] += unpk(sv.x);
            a[1] += unpk(sv.y);
            a[2] += unpk(sv.z);
            a[3] += unpk(sv.w);
        }
        uint2 lo, hi;
        lo.x = (u32)f2bf(a[0].x) | ((u32)f2bf(a[0].y) << 16);
        lo.y = (u32)f2bf(a[1].x) | ((u32)f2bf(a[1].y) << 16);
        hi.x = (u32)f2bf(a[2].x) | ((u32)f2bf(a[2].y) << 16);
        hi.y = (u32)f2bf(a[3].x) | ((u32)f2bf(a[3].y) << 16);
        *(uint2*)&As[ln * 140 + d8]     = lo;
        *(uint2*)&As[ln * 140 + d8 + 4] = hi;
    }
    __syncthreads();

    // ---- phase 2: MFMA gemm, 32x128 output; B-fragments straight from
    // global (L2-resident 32 KB, shared by all blocks; MFMA ~1% of time) ----
    const int wave = t >> 6;           // 0..3 -> 32-col slab
    const int lane = t & 63;
    const int q    = lane >> 4;
    const int m    = lane & 15;
    const int wc   = wave * 32;

    f32x4 acc[2][2] = {};
    #pragma unroll
    for (int kb = 0; kb < 4; ++kb) {
        int ak = kb * 32 + q * 8;
        short8 af[2];
        #pragma unroll
        for (int rg = 0; rg < 2; ++rg)
            af[rg] = *(const short8*)&As[(rg * 16 + m) * 140 + ak];
        #pragma unroll
        for (int ct = 0; ct < 2; ++ct) {
            short8 bf = *(const short8*)(Wtb + (wc + ct * 16 + m) * D + ak);
            #pragma unroll
            for (int rg = 0; rg < 2; ++rg)
                acc[rg][ct] = __builtin_amdgcn_mfma_f32_16x16x32_bf16(
                    af[rg], bf, acc[rg][ct], 0, 0, 0);
        }
    }

    #pragma unroll
    for (int ct = 0; ct < 2; ++ct) {
        int col = wc + ct * 16 + m;
        float bc = bias[col];
        #pragma unroll
        for (int rg = 0; rg < 2; ++rg) {
            #pragma unroll
            for (int r = 0; r < 4; ++r) {
                int grow = row0 + rg * 16 + q * 4 + r;
                if (grow < NN) {
                    float v = acc[rg][ct][r] + bc;
                    if (relu) v = fmaxf(0.f, v);
                    if (outb) outb[(size_t)grow * D + col] = f2bf(v);
                    else __builtin_nontemporal_store(v, outf + (size_t)grow * D + col);
                }
            }
        }
    }
}

extern "C" void kernel_launch(void* const* d_in, const int* in_sizes, int n_in,
                              void* d_out, int out_size, void* d_ws, size_t ws_size,
                              hipStream_t stream)
{
    const float* x   = (const float*)d_in[0];
    const int*   ei  = (const int*)  d_in[1];
    const float* ew  = (const float*)d_in[2];
    const float* We1 = (const float*)d_in[3];
    const float* be1 = (const float*)d_in[4];
    const float* W1  = (const float*)d_in[5];
    const float* b1  = (const float*)d_in[6];
    const float* We2 = (const float*)d_in[7];
    const float* be2 = (const float*)d_in[8];
    const float* W2  = (const float*)d_in[9];
    const float* b2  = (const float*)d_in[10];

    float* out = (float*)d_out;

    // workspace (~40 MB)
    ushort* xb   = (ushort*)d_ws;                    // NN*D bf16
    ushort* hb   = xb + (size_t)NN * D;              // NN*D
    ushort* Wt1  = hb + (size_t)NN * D;              // 16384
    ushort* Wt2  = Wt1 + D * D;                      // 16384
    u64*   stage = (u64*)(Wt2 + D * D);              // NE u64
    int*   G     = (int*)(stage + NE);               // NC*NB
    int*   B     = G + NC * NB;                      // NB+1
    int*   off   = B + NB + 2;                       // NN+1

    const int* src = ei;
    const int* dst = ei + NE;

    // ---- hist (LDS atomics) + W transpose ----
    hist_w<<<NC + 8, 256, 0, stream>>>(W1, W2, Wt1, Wt2, dst, G);

    // ---- bucket-sorted CSR build (scan folded into scatter) ----
    bucket_scatter<<<NC, 1024, 0, stream>>>(src, dst, ew, G, B, stage);
    bucket_csr_cast<<<NB, 256, 0, stream>>>(B, stage, off, x, xb);

    // ---- layer 1 (fused aggregate + gemm) ----
    gine_layer<<<GG, 256, 0, stream>>>(xb, off, stage, We1, be1, Wt1, b1,
                                       nullptr, hb, 1);

    // ---- layer 2 (fused aggregate + gemm) ----
    gine_layer<<<GG, 256, 0, stream>>>(hb, off, stage, We2, be2, Wt2, b2,
                                       out, nullptr, 0);
}